// Round 2
// baseline (256.902 us; speedup 1.0000x reference)
//
#include <hip/hip_runtime.h>

typedef __bf16 bf16x8 __attribute__((ext_vector_type(8)));
typedef float f32x4 __attribute__((ext_vector_type(4)));

constexpr int SEQ = 2048;
constexpr int DMODEL = 1024;

// ---------------- transpose + fp32->bf16 convert: dst[C][R] = (bf16)src[R][C] ----------------
__global__ __launch_bounds__(256) void transpose_cvt(const float* __restrict__ src,
                                                     __bf16* __restrict__ dst,
                                                     int R, int C) {
  __shared__ __bf16 tile[64][72];
  int c0 = blockIdx.x * 64, r0 = blockIdx.y * 64;
  int t = threadIdx.x;
#pragma unroll
  for (int p = 0; p < 2; ++p) {
    int flat = p * 256 + t;
    int i = flat >> 3;
    int j8 = (flat & 7) * 8;
    const float* sp = &src[(size_t)(r0 + i) * C + c0 + j8];
    float4 f0 = *reinterpret_cast<const float4*>(sp);
    float4 f1 = *reinterpret_cast<const float4*>(sp + 4);
    tile[i][j8 + 0] = (__bf16)f0.x; tile[i][j8 + 1] = (__bf16)f0.y;
    tile[i][j8 + 2] = (__bf16)f0.z; tile[i][j8 + 3] = (__bf16)f0.w;
    tile[i][j8 + 4] = (__bf16)f1.x; tile[i][j8 + 5] = (__bf16)f1.y;
    tile[i][j8 + 6] = (__bf16)f1.z; tile[i][j8 + 7] = (__bf16)f1.w;
  }
  __syncthreads();
#pragma unroll
  for (int p = 0; p < 2; ++p) {
    int flat = p * 256 + t;
    int i = flat >> 3;
    int j8 = (flat & 7) * 8;
    alignas(16) __bf16 tmp[8];
#pragma unroll
    for (int jj = 0; jj < 8; ++jj) tmp[jj] = tile[j8 + jj][i];
    *reinterpret_cast<uint4*>(&dst[(size_t)(c0 + i) * R + r0 + j8]) =
        *reinterpret_cast<const uint4*>(tmp);
  }
}

// ---------------- GEMM: C[M][N] = A[M][K] * BT[N][K]^T ----------------
// A: fp32 or bf16 (converted to bf16 at staging). BT: bf16. C: bf16 or fp32.
template <typename AT, typename CT>
__global__ __launch_bounds__(256) void gemm_bt(const AT* __restrict__ A,
                                               const __bf16* __restrict__ BT,
                                               CT* __restrict__ C,
                                               int M, int N, int K, int lda, int ldc) {
  __shared__ __bf16 A_lds[128][72];
  __shared__ __bf16 B_lds[128][72];
  int tid = threadIdx.x;
  int lane = tid & 63, w = tid >> 6;
  int g = lane >> 4, l15 = lane & 15;
  int wr = w >> 1, wc = w & 1;
  int m0 = blockIdx.x * 128, n0 = blockIdx.y * 128;

  f32x4 acc[4][4] = {};

  for (int k0 = 0; k0 < K; k0 += 64) {
    __syncthreads();
#pragma unroll
    for (int p = 0; p < 4; ++p) {
      int flat = p * 256 + tid;
      int r = flat >> 3;
      int c8 = (flat & 7) * 8;
      if constexpr (sizeof(AT) == 4) {
        const float* ap = &A[(size_t)(m0 + r) * lda + k0 + c8];
        float4 f0 = *reinterpret_cast<const float4*>(ap);
        float4 f1 = *reinterpret_cast<const float4*>(ap + 4);
        alignas(16) __bf16 tmp[8];
        tmp[0] = (__bf16)f0.x; tmp[1] = (__bf16)f0.y; tmp[2] = (__bf16)f0.z; tmp[3] = (__bf16)f0.w;
        tmp[4] = (__bf16)f1.x; tmp[5] = (__bf16)f1.y; tmp[6] = (__bf16)f1.z; tmp[7] = (__bf16)f1.w;
        *reinterpret_cast<uint4*>(&A_lds[r][c8]) = *reinterpret_cast<const uint4*>(tmp);
      } else {
        *reinterpret_cast<uint4*>(&A_lds[r][c8]) =
            *reinterpret_cast<const uint4*>(&A[(size_t)(m0 + r) * lda + k0 + c8]);
      }
      *reinterpret_cast<uint4*>(&B_lds[r][c8]) =
          *reinterpret_cast<const uint4*>(&BT[(size_t)(n0 + r) * K + k0 + c8]);
    }
    __syncthreads();
#pragma unroll
    for (int kk = 0; kk < 2; ++kk) {
      bf16x8 a[4], bb[4];
#pragma unroll
      for (int m = 0; m < 4; ++m)
        a[m] = *reinterpret_cast<const bf16x8*>(&A_lds[wr * 64 + m * 16 + l15][kk * 32 + g * 8]);
#pragma unroll
      for (int n = 0; n < 4; ++n)
        bb[n] = *reinterpret_cast<const bf16x8*>(&B_lds[wc * 64 + n * 16 + l15][kk * 32 + g * 8]);
#pragma unroll
      for (int m = 0; m < 4; ++m)
#pragma unroll
        for (int n = 0; n < 4; ++n)
          acc[m][n] = __builtin_amdgcn_mfma_f32_16x16x32_bf16(a[m], bb[n], acc[m][n], 0, 0, 0);
    }
  }

#pragma unroll
  for (int m = 0; m < 4; ++m)
#pragma unroll
    for (int n = 0; n < 4; ++n)
#pragma unroll
      for (int r = 0; r < 4; ++r) {
        int row = m0 + wr * 64 + m * 16 + 4 * g + r;
        int col = n0 + wc * 64 + n * 16 + l15;
        C[(size_t)row * ldc + col] = (CT)acc[m][n][r];
      }
}

// ---------------- RoPE in-place on qkv [4096][3072] (q and k blocks) ----------------
__global__ __launch_bounds__(256) void rope_kernel(__bf16* __restrict__ qkv) {
  int idx = blockIdx.x * blockDim.x + threadIdx.x;  // 0 .. 4096*1024-1
  int d = idx & 31;
  int h = (idx >> 5) & 15;
  int qk = (idx >> 9) & 1;
  int tok = idx >> 10;       // 0..4095
  int t = tok & (SEQ - 1);   // position in sequence
  size_t base = (size_t)tok * 3072 + (size_t)qk * 1024 + h * 64 + d;
  float x1 = (float)qkv[base];
  float x2 = (float)qkv[base + 32];
  // theta = 10000^(-d/32) = exp2(-d * log2(10000)/32)
  float theta = exp2f(-(float)d * 0.41524101186092953f);
  float ang = (float)t * theta;
  float s, c;
  __sincosf(ang, &s, &c);
  qkv[base] = (__bf16)(x1 * c - x2 * s);
  qkv[base + 32] = (__bf16)(x1 * s + x2 * c);
}

// ---------------- causal flash attention; writes y into q-slot of qkv ----------------
// grid: (SEQ/64, B*NH); block 256 (4 waves, 16 q-rows per wave)
__global__ __launch_bounds__(256) void attn_kernel(__bf16* __restrict__ qkv) {
  __shared__ __bf16 K_lds[64][72];    // [s][d]
  __shared__ __bf16 Vt_lds[64][72];   // [d][s]
  __shared__ __bf16 P_lds[4][16][72]; // per-wave P stripe [q][s]

  int tid = threadIdx.x;
  int w = tid >> 6, lane = tid & 63;
  int g = lane >> 4, l15 = lane & 15;
  int qb = blockIdx.x;
  int bh = blockIdx.y;
  int b = bh >> 4, h = bh & 15;

  __bf16* qbase = qkv + (size_t)b * SEQ * 3072 + h * 64;
  const __bf16* kbase = qbase + 1024;
  const __bf16* vbase = qbase + 2048;

  int q_frag_row = qb * 64 + w * 16 + l15;
  bf16x8 qf[2];
  qf[0] = *reinterpret_cast<const bf16x8*>(qbase + (size_t)q_frag_row * 3072 + g * 8);
  qf[1] = *reinterpret_cast<const bf16x8*>(qbase + (size_t)q_frag_row * 3072 + 32 + g * 8);

  f32x4 o_acc[4] = {};
  float m_run[4], l_run[4];
#pragma unroll
  for (int r = 0; r < 4; ++r) { m_run[r] = -1e30f; l_run[r] = 0.f; }

  int q_row0 = qb * 64 + w * 16;

  for (int jb = 0; jb <= qb; ++jb) {
    __syncthreads();
#pragma unroll
    for (int p = 0; p < 2; ++p) {
      int flat = p * 256 + tid;
      int s = flat >> 3;
      int c8 = (flat & 7) * 8;
      *reinterpret_cast<uint4*>(&K_lds[s][c8]) =
          *reinterpret_cast<const uint4*>(kbase + (size_t)(jb * 64 + s) * 3072 + c8);
      uint4 vv = *reinterpret_cast<const uint4*>(vbase + (size_t)(jb * 64 + s) * 3072 + c8);
      const __bf16* vp = reinterpret_cast<const __bf16*>(&vv);
#pragma unroll
      for (int jj = 0; jj < 8; ++jj) Vt_lds[c8 + jj][s] = vp[jj];
    }
    __syncthreads();

    // S = Q K^T
    f32x4 s_acc[4] = {};
#pragma unroll
    for (int f = 0; f < 4; ++f) {
#pragma unroll
      for (int kk = 0; kk < 2; ++kk) {
        bf16x8 kf = *reinterpret_cast<const bf16x8*>(&K_lds[f * 16 + l15][kk * 32 + g * 8]);
        s_acc[f] = __builtin_amdgcn_mfma_f32_16x16x32_bf16(qf[kk], kf, s_acc[f], 0, 0, 0);
      }
    }

    float pv[4][4];
    float tmax[4] = {-1e30f, -1e30f, -1e30f, -1e30f};
#pragma unroll
    for (int f = 0; f < 4; ++f) {
      int s_g = jb * 64 + f * 16 + l15;
#pragma unroll
      for (int r = 0; r < 4; ++r) {
        float sv = s_acc[f][r] * 0.125f;
        int q_g = q_row0 + 4 * g + r;
        sv = (s_g > q_g) ? -1e30f : sv;
        pv[f][r] = sv;
        tmax[r] = fmaxf(tmax[r], sv);
      }
    }
#pragma unroll
    for (int r = 0; r < 4; ++r) {
      float m = tmax[r];
      m = fmaxf(m, __shfl_xor(m, 1));
      m = fmaxf(m, __shfl_xor(m, 2));
      m = fmaxf(m, __shfl_xor(m, 4));
      m = fmaxf(m, __shfl_xor(m, 8));
      tmax[r] = m;
    }
    float alpha[4], rsum[4];
#pragma unroll
    for (int r = 0; r < 4; ++r) {
      float m_new = fmaxf(m_run[r], tmax[r]);
      alpha[r] = __expf(m_run[r] - m_new);
      m_run[r] = m_new;
      rsum[r] = 0.f;
    }
#pragma unroll
    for (int f = 0; f < 4; ++f) {
#pragma unroll
      for (int r = 0; r < 4; ++r) {
        float p = __expf(pv[f][r] - m_run[r]);
        rsum[r] += p;
        P_lds[w][4 * g + r][f * 16 + l15] = (__bf16)p;
      }
    }
#pragma unroll
    for (int r = 0; r < 4; ++r) {
      float s = rsum[r];
      s += __shfl_xor(s, 1);
      s += __shfl_xor(s, 2);
      s += __shfl_xor(s, 4);
      s += __shfl_xor(s, 8);
      l_run[r] = l_run[r] * alpha[r] + s;
    }
#pragma unroll
    for (int n = 0; n < 4; ++n)
#pragma unroll
      for (int r = 0; r < 4; ++r) o_acc[n][r] *= alpha[r];

    asm volatile("s_waitcnt lgkmcnt(0)" ::: "memory");
    __builtin_amdgcn_sched_barrier(0);

    // O += P V
#pragma unroll
    for (int kk = 0; kk < 2; ++kk) {
      bf16x8 pa = *reinterpret_cast<const bf16x8*>(&P_lds[w][l15][kk * 32 + g * 8]);
#pragma unroll
      for (int n = 0; n < 4; ++n) {
        bf16x8 vf = *reinterpret_cast<const bf16x8*>(&Vt_lds[n * 16 + l15][kk * 32 + g * 8]);
        o_acc[n] = __builtin_amdgcn_mfma_f32_16x16x32_bf16(pa, vf, o_acc[n], 0, 0, 0);
      }
    }
  }

  // epilogue: y = O / l, written into the q-slot (this block's exclusive region)
#pragma unroll
  for (int r = 0; r < 4; ++r) {
    float inv = 1.0f / l_run[r];
    int qrow = q_row0 + 4 * g + r;
#pragma unroll
    for (int n = 0; n < 4; ++n) {
      qbase[(size_t)qrow * 3072 + n * 16 + l15] = (__bf16)(o_acc[n][r] * inv);
    }
  }
}

extern "C" void kernel_launch(void* const* d_in, const int* in_sizes, int n_in,
                              void* d_out, int out_size, void* d_ws, size_t ws_size,
                              hipStream_t stream) {
  const float* x = (const float*)d_in[0];       // [4096][1024] fp32
  const float* Wqkv = (const float*)d_in[1];    // [1024][3072] fp32
  const float* Wo = (const float*)d_in[2];      // [1024][1024] fp32
  float* out = (float*)d_out;                   // [4096][1024] fp32

  __bf16* ws = (__bf16*)d_ws;
  __bf16* WqkvT = ws;                           // [3072][1024] bf16 (6 MB)
  __bf16* WoT = WqkvT + 3072 * 1024;            // [1024][1024] bf16 (2 MB)
  __bf16* qkv = WoT + 1024 * 1024;              // [4096][3072] bf16 (24 MB)

  transpose_cvt<<<dim3(48, 16), 256, 0, stream>>>(Wqkv, WqkvT, 1024, 3072);
  transpose_cvt<<<dim3(16, 16), 256, 0, stream>>>(Wo, WoT, 1024, 1024);

  // qkv = bf16(x) @ bf16(Wqkv)
  gemm_bt<float, __bf16><<<dim3(32, 24), 256, 0, stream>>>(x, WqkvT, qkv,
                                                           4096, 3072, 1024, 1024, 3072);
  rope_kernel<<<16384, 256, 0, stream>>>(qkv);

  // attention: y overwrites q-slot of qkv
  attn_kernel<<<dim3(SEQ / 64, 32), 256, 0, stream>>>(qkv);

  // out = y @ Wo  (A = q-slot of qkv, lda=3072; C fp32)
  gemm_bt<__bf16, float><<<dim3(32, 8), 256, 0, stream>>>(qkv, WoT, out,
                                                          4096, 1024, 1024, 3072, 1024);
}

// Round 3
// 170.115 us; speedup vs baseline: 1.5102x; 1.5102x over previous
//
#include <hip/hip_runtime.h>

typedef __bf16 bf16x8 __attribute__((ext_vector_type(8)));
typedef float f32x4 __attribute__((ext_vector_type(4)));

constexpr int SEQ = 2048;
constexpr int DMODEL = 1024;

// ---------------- transpose + fp32->bf16 convert: dst[C][R] = (bf16)src[R][C] ----------------
__global__ __launch_bounds__(256) void transpose_cvt(const float* __restrict__ src,
                                                     __bf16* __restrict__ dst,
                                                     int R, int C) {
  __shared__ __bf16 tile[64][72];
  int c0 = blockIdx.x * 64, r0 = blockIdx.y * 64;
  int t = threadIdx.x;
#pragma unroll
  for (int p = 0; p < 2; ++p) {
    int flat = p * 256 + t;
    int i = flat >> 3;
    int j8 = (flat & 7) * 8;
    const float* sp = &src[(size_t)(r0 + i) * C + c0 + j8];
    float4 f0 = *reinterpret_cast<const float4*>(sp);
    float4 f1 = *reinterpret_cast<const float4*>(sp + 4);
    tile[i][j8 + 0] = (__bf16)f0.x; tile[i][j8 + 1] = (__bf16)f0.y;
    tile[i][j8 + 2] = (__bf16)f0.z; tile[i][j8 + 3] = (__bf16)f0.w;
    tile[i][j8 + 4] = (__bf16)f1.x; tile[i][j8 + 5] = (__bf16)f1.y;
    tile[i][j8 + 6] = (__bf16)f1.z; tile[i][j8 + 7] = (__bf16)f1.w;
  }
  __syncthreads();
#pragma unroll
  for (int p = 0; p < 2; ++p) {
    int flat = p * 256 + t;
    int i = flat >> 3;
    int j8 = (flat & 7) * 8;
    alignas(16) __bf16 tmp[8];
#pragma unroll
    for (int jj = 0; jj < 8; ++jj) tmp[jj] = tile[j8 + jj][i];
    *reinterpret_cast<uint4*>(&dst[(size_t)(c0 + i) * R + r0 + j8]) =
        *reinterpret_cast<const uint4*>(tmp);
  }
}

// ---------------- GEMM: C[M][N] = A[M][K] * BT[N][K]^T ----------------
template <typename AT, typename CT>
__global__ __launch_bounds__(256) void gemm_bt(const AT* __restrict__ A,
                                               const __bf16* __restrict__ BT,
                                               CT* __restrict__ C,
                                               int M, int N, int K, int lda, int ldc) {
  __shared__ __bf16 A_lds[128][72];
  __shared__ __bf16 B_lds[128][72];
  int tid = threadIdx.x;
  int lane = tid & 63, w = tid >> 6;
  int g = lane >> 4, l15 = lane & 15;
  int wr = w >> 1, wc = w & 1;
  int m0 = blockIdx.x * 128, n0 = blockIdx.y * 128;

  f32x4 acc[4][4] = {};

  for (int k0 = 0; k0 < K; k0 += 64) {
    __syncthreads();
#pragma unroll
    for (int p = 0; p < 4; ++p) {
      int flat = p * 256 + tid;
      int r = flat >> 3;
      int c8 = (flat & 7) * 8;
      if constexpr (sizeof(AT) == 4) {
        const float* ap = &A[(size_t)(m0 + r) * lda + k0 + c8];
        float4 f0 = *reinterpret_cast<const float4*>(ap);
        float4 f1 = *reinterpret_cast<const float4*>(ap + 4);
        alignas(16) __bf16 tmp[8];
        tmp[0] = (__bf16)f0.x; tmp[1] = (__bf16)f0.y; tmp[2] = (__bf16)f0.z; tmp[3] = (__bf16)f0.w;
        tmp[4] = (__bf16)f1.x; tmp[5] = (__bf16)f1.y; tmp[6] = (__bf16)f1.z; tmp[7] = (__bf16)f1.w;
        *reinterpret_cast<uint4*>(&A_lds[r][c8]) = *reinterpret_cast<const uint4*>(tmp);
      } else {
        *reinterpret_cast<uint4*>(&A_lds[r][c8]) =
            *reinterpret_cast<const uint4*>(&A[(size_t)(m0 + r) * lda + k0 + c8]);
      }
      *reinterpret_cast<uint4*>(&B_lds[r][c8]) =
          *reinterpret_cast<const uint4*>(&BT[(size_t)(n0 + r) * K + k0 + c8]);
    }
    __syncthreads();
#pragma unroll
    for (int kk = 0; kk < 2; ++kk) {
      bf16x8 a[4], bb[4];
#pragma unroll
      for (int m = 0; m < 4; ++m)
        a[m] = *reinterpret_cast<const bf16x8*>(&A_lds[wr * 64 + m * 16 + l15][kk * 32 + g * 8]);
#pragma unroll
      for (int n = 0; n < 4; ++n)
        bb[n] = *reinterpret_cast<const bf16x8*>(&B_lds[wc * 64 + n * 16 + l15][kk * 32 + g * 8]);
#pragma unroll
      for (int m = 0; m < 4; ++m)
#pragma unroll
        for (int n = 0; n < 4; ++n)
          acc[m][n] = __builtin_amdgcn_mfma_f32_16x16x32_bf16(a[m], bb[n], acc[m][n], 0, 0, 0);
    }
  }

#pragma unroll
  for (int m = 0; m < 4; ++m)
#pragma unroll
    for (int n = 0; n < 4; ++n)
#pragma unroll
      for (int r = 0; r < 4; ++r) {
        int row = m0 + wr * 64 + m * 16 + 4 * g + r;
        int col = n0 + wc * 64 + n * 16 + l15;
        C[(size_t)row * ldc + col] = (CT)acc[m][n][r];
      }
}

// ---------------- RoPE in-place on qkv [4096][3072] (q and k blocks) ----------------
__global__ __launch_bounds__(256) void rope_kernel(__bf16* __restrict__ qkv) {
  int idx = blockIdx.x * blockDim.x + threadIdx.x;
  int d = idx & 31;
  int h = (idx >> 5) & 15;
  int qk = (idx >> 9) & 1;
  int tok = idx >> 10;
  int t = tok & (SEQ - 1);
  size_t base = (size_t)tok * 3072 + (size_t)qk * 1024 + h * 64 + d;
  float x1 = (float)qkv[base];
  float x2 = (float)qkv[base + 32];
  float theta = exp2f(-(float)d * 0.41524101186092953f);
  float ang = (float)t * theta;
  float s, c;
  __sincosf(ang, &s, &c);
  qkv[base] = (__bf16)(x1 * c - x2 * s);
  qkv[base + 32] = (__bf16)(x1 * s + x2 * c);
}

// ---------------- causal flash attention; writes y into q-slot of qkv ----------------
// 1D grid of 1024 blocks, heavy (high-qb) blocks first. 4 waves, 16 q-rows/wave.
// Vt_lds XOR-swizzled: element (d,s) stored at [d][s ^ (((d>>3)&7)*8)].
__global__ __launch_bounds__(256) void attn_kernel(__bf16* __restrict__ qkv) {
  __shared__ __bf16 K_lds[64][72];
  __shared__ __bf16 Vt_lds[64][72];
  __shared__ __bf16 P_lds[4][16][72];

  int tid = threadIdx.x;
  int w = tid >> 6, lane = tid & 63;
  int g = lane >> 4, l15 = lane & 15;
  int idx = blockIdx.x;
  int qb = 31 - (idx >> 5);   // heavy blocks dispatch first
  int bh = idx & 31;
  int b = bh >> 4, h = bh & 15;

  __bf16* qbase = qkv + (size_t)b * SEQ * 3072 + h * 64;
  const __bf16* kbase = qbase + 1024;
  const __bf16* vbase = qbase + 2048;

  // per-thread staging coords: p in {0,1}: s = p*32 + (tid>>3), col block c8
  int c8 = (tid & 7) * 8;
  int srow = tid >> 3;
  int vswz = c8;  // ((d>>3)&7)*8 with d>>3 == tid&7

  int q_frag_row = qb * 64 + w * 16 + l15;
  bf16x8 qf[2];
  qf[0] = *reinterpret_cast<const bf16x8*>(qbase + (size_t)q_frag_row * 3072 + g * 8);
  qf[1] = *reinterpret_cast<const bf16x8*>(qbase + (size_t)q_frag_row * 3072 + 32 + g * 8);

  f32x4 o_acc[4] = {};
  float m_run[4], l_run[4];
#pragma unroll
  for (int r = 0; r < 4; ++r) { m_run[r] = -1e30f; l_run[r] = 0.f; }

  int q_row0 = qb * 64 + w * 16;

  // initial stage (jb = 0)
#pragma unroll
  for (int p = 0; p < 2; ++p) {
    int s = p * 32 + srow;
    *reinterpret_cast<uint4*>(&K_lds[s][c8]) =
        *reinterpret_cast<const uint4*>(kbase + (size_t)s * 3072 + c8);
    uint4 vv = *reinterpret_cast<const uint4*>(vbase + (size_t)s * 3072 + c8);
    const __bf16* vp = reinterpret_cast<const __bf16*>(&vv);
#pragma unroll
    for (int jj = 0; jj < 8; ++jj) Vt_lds[c8 + jj][s ^ vswz] = vp[jj];
  }
  __syncthreads();

  for (int jb = 0; jb <= qb; ++jb) {
    bool pre = (jb < qb);
    uint4 kpre[2], vpre[2];
    if (pre) {
#pragma unroll
      for (int p = 0; p < 2; ++p) {
        int s = (jb + 1) * 64 + p * 32 + srow;
        kpre[p] = *reinterpret_cast<const uint4*>(kbase + (size_t)s * 3072 + c8);
        vpre[p] = *reinterpret_cast<const uint4*>(vbase + (size_t)s * 3072 + c8);
      }
    }

    // S = Q K^T
    f32x4 s_acc[4] = {};
    __builtin_amdgcn_s_setprio(1);
#pragma unroll
    for (int f = 0; f < 4; ++f) {
#pragma unroll
      for (int kk = 0; kk < 2; ++kk) {
        bf16x8 kf = *reinterpret_cast<const bf16x8*>(&K_lds[f * 16 + l15][kk * 32 + g * 8]);
        s_acc[f] = __builtin_amdgcn_mfma_f32_16x16x32_bf16(qf[kk], kf, s_acc[f], 0, 0, 0);
      }
    }
    __builtin_amdgcn_s_setprio(0);

    float pv[4][4];
    float tmax[4] = {-1e30f, -1e30f, -1e30f, -1e30f};
    if (jb == qb) {  // diagonal tile: apply causal mask (wave-uniform branch)
#pragma unroll
      for (int f = 0; f < 4; ++f) {
        int s_g = jb * 64 + f * 16 + l15;
#pragma unroll
        for (int r = 0; r < 4; ++r) {
          float sv = s_acc[f][r] * 0.125f;
          int q_g = q_row0 + 4 * g + r;
          sv = (s_g > q_g) ? -1e30f : sv;
          pv[f][r] = sv;
          tmax[r] = fmaxf(tmax[r], sv);
        }
      }
    } else {
#pragma unroll
      for (int f = 0; f < 4; ++f)
#pragma unroll
        for (int r = 0; r < 4; ++r) {
          float sv = s_acc[f][r] * 0.125f;
          pv[f][r] = sv;
          tmax[r] = fmaxf(tmax[r], sv);
        }
    }
#pragma unroll
    for (int r = 0; r < 4; ++r) {
      float m = tmax[r];
      m = fmaxf(m, __shfl_xor(m, 1));
      m = fmaxf(m, __shfl_xor(m, 2));
      m = fmaxf(m, __shfl_xor(m, 4));
      m = fmaxf(m, __shfl_xor(m, 8));
      tmax[r] = m;
    }
    float alpha[4], rsum[4];
#pragma unroll
    for (int r = 0; r < 4; ++r) {
      float m_new = fmaxf(m_run[r], tmax[r]);
      alpha[r] = __expf(m_run[r] - m_new);
      m_run[r] = m_new;
      rsum[r] = 0.f;
    }
#pragma unroll
    for (int f = 0; f < 4; ++f) {
#pragma unroll
      for (int r = 0; r < 4; ++r) {
        float p = __expf(pv[f][r] - m_run[r]);
        rsum[r] += p;
        P_lds[w][4 * g + r][f * 16 + l15] = (__bf16)p;
      }
    }
#pragma unroll
    for (int r = 0; r < 4; ++r) {
      float s = rsum[r];
      s += __shfl_xor(s, 1);
      s += __shfl_xor(s, 2);
      s += __shfl_xor(s, 4);
      s += __shfl_xor(s, 8);
      l_run[r] = l_run[r] * alpha[r] + s;
    }
#pragma unroll
    for (int n = 0; n < 4; ++n)
#pragma unroll
      for (int r = 0; r < 4; ++r) o_acc[n][r] *= alpha[r];

    asm volatile("s_waitcnt lgkmcnt(0)" ::: "memory");
    __builtin_amdgcn_sched_barrier(0);

    // O += P V  (V read back through the same XOR swizzle)
    __builtin_amdgcn_s_setprio(1);
#pragma unroll
    for (int kk = 0; kk < 2; ++kk) {
      bf16x8 pa = *reinterpret_cast<const bf16x8*>(&P_lds[w][l15][kk * 32 + g * 8]);
#pragma unroll
      for (int n = 0; n < 4; ++n) {
        int row = n * 16 + l15;
        int col = (kk * 32 + g * 8) ^ (((row >> 3) & 7) * 8);
        bf16x8 vf = *reinterpret_cast<const bf16x8*>(&Vt_lds[row][col]);
        o_acc[n] = __builtin_amdgcn_mfma_f32_16x16x32_bf16(pa, vf, o_acc[n], 0, 0, 0);
      }
    }
    __builtin_amdgcn_s_setprio(0);

    if (pre) {
      __syncthreads();  // all waves done reading K_lds/Vt_lds
#pragma unroll
      for (int p = 0; p < 2; ++p) {
        int s = p * 32 + srow;
        *reinterpret_cast<uint4*>(&K_lds[s][c8]) = kpre[p];
        const __bf16* vp = reinterpret_cast<const __bf16*>(&vpre[p]);
#pragma unroll
        for (int jj = 0; jj < 8; ++jj) Vt_lds[c8 + jj][s ^ vswz] = vp[jj];
      }
      __syncthreads();
    }
  }

  // epilogue: y = O / l into the q-slot (this block's exclusive region)
#pragma unroll
  for (int r = 0; r < 4; ++r) {
    float inv = 1.0f / l_run[r];
    int qrow = q_row0 + 4 * g + r;
#pragma unroll
    for (int n = 0; n < 4; ++n) {
      qbase[(size_t)qrow * 3072 + n * 16 + l15] = (__bf16)(o_acc[n][r] * inv);
    }
  }
}

extern "C" void kernel_launch(void* const* d_in, const int* in_sizes, int n_in,
                              void* d_out, int out_size, void* d_ws, size_t ws_size,
                              hipStream_t stream) {
  const float* x = (const float*)d_in[0];
  const float* Wqkv = (const float*)d_in[1];
  const float* Wo = (const float*)d_in[2];
  float* out = (float*)d_out;

  __bf16* ws = (__bf16*)d_ws;
  __bf16* WqkvT = ws;                           // [3072][1024]
  __bf16* WoT = WqkvT + 3072 * 1024;            // [1024][1024]
  __bf16* qkv = WoT + 1024 * 1024;              // [4096][3072]

  transpose_cvt<<<dim3(48, 16), 256, 0, stream>>>(Wqkv, WqkvT, 1024, 3072);
  transpose_cvt<<<dim3(16, 16), 256, 0, stream>>>(Wo, WoT, 1024, 1024);

  gemm_bt<float, __bf16><<<dim3(32, 24), 256, 0, stream>>>(x, WqkvT, qkv,
                                                           4096, 3072, 1024, 1024, 3072);
  rope_kernel<<<16384, 256, 0, stream>>>(qkv);

  attn_kernel<<<1024, 256, 0, stream>>>(qkv);

  gemm_bt<__bf16, float><<<dim3(32, 8), 256, 0, stream>>>(qkv, WoT, out,
                                                          4096, 1024, 1024, 3072, 1024);
}